// Round 4
// baseline (169.754 us; speedup 1.0000x reference)
//
#include <hip/hip_runtime.h>

#define NB     2
#define SEQ    2048
#define EMBED  1024
#define HDIM   64
#define MAGIC  0x3C3C3C3Cu   // != 0xAAAAAAAA ws-poison

// One fused kernel, grid = 256 blocks (== CU count; all co-resident, so
// device-scope flag spin cannot deadlock: total residency capacity ~2048
// blocks >> 256, every block gets dispatched while others spin).
//
// block b: batch n = b>>7, j = b&127
//   P1: part[b][:] = sum of values rows [j*16, j*16+16)          (16 MB read)
//   P2: blocks with j%8==0 (16/batch): reduce 128 partials over a
//       64-col slice -> Sv[n][slice]                              (L2 traffic)
//   P3: all blocks: Vflat = Wv @ Sv (per head), 16 Wo-row dots for
//       stripe s16 = j>>1, broadcast those 16 cols over row-half j&1 (16 MB write)
__global__ __launch_bounds__(256) void fused_k(
    const float* __restrict__ vals, const float* __restrict__ Wv,
    const float* __restrict__ Wo,  const float* __restrict__ bo,
    float* __restrict__ part, float* __restrict__ Sv,
    unsigned* __restrict__ flag1, unsigned* __restrict__ flag2,
    float4* __restrict__ out4)
{
    const int b = blockIdx.x;
    const int n = b >> 7;
    const int j = b & 127;
    const int t = threadIdx.x;

    __shared__ float svl[EMBED];
    __shared__ float vfl[EMBED];
    __shared__ float red[256];
    __shared__ __align__(16) float rsl[16];

    // ---------------- P1: partial column-sum of this block's 16 rows
    {
        const float4* base = reinterpret_cast<const float4*>(vals)
                           + (size_t)(n * SEQ + j * 16) * (EMBED / 4);
        float4 acc = make_float4(0.f, 0.f, 0.f, 0.f);
        #pragma unroll
        for (int r = 0; r < 16; ++r) {
            float4 v = base[(size_t)r * (EMBED / 4) + t];
            acc.x += v.x; acc.y += v.y; acc.z += v.z; acc.w += v.w;
        }
        reinterpret_cast<float4*>(part)[(size_t)b * (EMBED / 4) + t] = acc;
    }
    __syncthreads();                       // drains vmcnt: part complete in L2
    if (t == 0)                            // agent release: L2 wb + flag set
        __hip_atomic_store(&flag1[b], MAGIC, __ATOMIC_RELEASE,
                           __HIP_MEMORY_SCOPE_AGENT);

    // ---------------- P2: 16 reducer blocks per batch build Sv
    if ((j & 7) == 0) {
        const int cs = j >> 3;             // col-slice 0..15 (64 floats)
        if (t < 128)
            while (__hip_atomic_load(&flag1[n * 128 + t], __ATOMIC_ACQUIRE,
                                     __HIP_MEMORY_SCOPE_AGENT) != MAGIC)
                __builtin_amdgcn_s_sleep(1);
        __syncthreads();
        const int i = cs * 64 + (t & 63);  // column
        const int g = t >> 6;              // 0..3
        float a = 0.f;
        #pragma unroll 4
        for (int c = g; c < 128; c += 4)
            a += part[(size_t)(n * 128 + c) * EMBED + i];
        red[t] = a;
        __syncthreads();
        if (t < 64)
            Sv[n * EMBED + cs * 64 + t] =
                red[t] + red[t + 64] + red[t + 128] + red[t + 192];
        __syncthreads();                   // drain Sv stores
        if (t == 0)
            __hip_atomic_store(&flag2[n * 16 + cs], MAGIC, __ATOMIC_RELEASE,
                               __HIP_MEMORY_SCOPE_AGENT);
    }

    // ---------------- P3: wait for Sv, then matvec + broadcast
    if (t < 16)
        while (__hip_atomic_load(&flag2[n * 16 + t], __ATOMIC_ACQUIRE,
                                 __HIP_MEMORY_SCOPE_AGENT) != MAGIC)
            __builtin_amdgcn_s_sleep(1);
    __syncthreads();
    __threadfence();                       // inv for the non-acquiring waves

    reinterpret_cast<float4*>(svl)[t] =
        reinterpret_cast<const float4*>(Sv + n * EMBED)[t];
    __syncthreads();

    // Vflat[h*64+d] = sum_e Wv[d][e] * Sv[h*64+e]
    for (int o = t; o < EMBED; o += 256) {
        const int h = o >> 6, d = o & 63;
        const float* wr = Wv + d * HDIM;
        const float* sr = svl + h * HDIM;
        float a = 0.f;
        #pragma unroll
        for (int e = 0; e < HDIM; ++e) a += wr[e] * sr[e];
        vfl[o] = a;
    }
    __syncthreads();

    // 16 outputs for stripe s16 (wave w -> 4 outputs)
    const int wave = t >> 6;
    const int lane = t & 63;
    const int s16  = j >> 1;               // 0..63: 16-col output stripe
    const int hh   = j & 1;                // row half: s in [hh*1024, hh*1024+1024)
    float4 vv[4];
    #pragma unroll
    for (int it = 0; it < 4; ++it)
        vv[it] = reinterpret_cast<const float4*>(vfl)[it * 64 + lane];

    const float4* Wo4 = reinterpret_cast<const float4*>(Wo);
    #pragma unroll
    for (int j2 = 0; j2 < 4; ++j2) {
        const int o = s16 * 16 + wave * 4 + j2;
        float acc = 0.f;
        #pragma unroll
        for (int it = 0; it < 4; ++it) {
            float4 w4 = Wo4[(size_t)o * (EMBED / 4) + it * 64 + lane];
            acc += w4.x * vv[it].x + w4.y * vv[it].y
                 + w4.z * vv[it].z + w4.w * vv[it].w;
        }
        #pragma unroll
        for (int off = 32; off >= 1; off >>= 1)
            acc += __shfl_xor(acc, off);
        if (lane == 0) rsl[wave * 4 + j2] = acc + bo[o];
    }
    __syncthreads();

    // broadcast 16 cols x 1024 rows: lane group of 4 covers 64B/row (full
    // sector); wave covers 16 rows/iter.
    const float4 val = reinterpret_cast<const float4*>(rsl)[t & 3];
    float4* op = out4 + (size_t)(n * SEQ + hh * 1024 + (t >> 2)) * (EMBED / 4)
               + s16 * 4 + (t & 3);
    #pragma unroll
    for (int k = 0; k < 16; ++k)
        op[(size_t)k * 64 * (EMBED / 4)] = val;
}

// ---------------------------------------------------------------------------
extern "C" void kernel_launch(void* const* d_in, const int* in_sizes, int n_in,
                              void* d_out, int out_size, void* d_ws, size_t ws_size,
                              hipStream_t stream) {
    // setup_inputs order: values, keys, queries, mask, Wv, Wk, Wq, Wo, bo
    const float* vals = (const float*)d_in[0];
    const float* Wv   = (const float*)d_in[4];
    const float* Wo   = (const float*)d_in[7];
    const float* bo   = (const float*)d_in[8];

    float*    part  = (float*)d_ws;                    // [256][1024] f32, 1 MB
    float*    Sv    = part + (size_t)256 * EMBED;      // [2][1024] f32
    unsigned* flag1 = (unsigned*)(Sv + NB * EMBED);    // [256]
    unsigned* flag2 = flag1 + 256;                     // [32]
    // flags start at 0xAAAAAAAA (harness re-poisons ws before every launch;
    // the fillBufferAligned dispatches in the trace confirm per-iteration) —
    // MAGIC differs, so spins are correct without any init node.

    fused_k<<<256, 256, 0, stream>>>(vals, Wv, Wo, bo, part, Sv,
                                     flag1, flag2, (float4*)d_out);
}

// Round 5
// 137.127 us; speedup vs baseline: 1.2379x; 1.2379x over previous
//
#include <hip/hip_runtime.h>

#define NB     2
#define SEQ    2048
#define EMBED  1024
#define HDIM   64
#define CH     128            // partials per batch (K2 reads CH*4KB = 512 KB)

// ---------------------------------------------------------------------------
// K1: part[n][c][e] = sum of 16 rows of values.
// grid = NB*CH = 256 blocks x 512 threads (8 waves/CU). Thread (g,c4) sums 8
// rows at float4-col c4; LDS combine of the two row-groups keeps CH at 128.
// 16 MB read, 1 MB write, no atomics.
// ---------------------------------------------------------------------------
__global__ __launch_bounds__(512) void colsum_part(const float* __restrict__ vals,
                                                   float* __restrict__ part) {
    const int b  = blockIdx.x;
    const int n  = b >> 7;               // 128 blocks per batch
    const int c  = b & 127;
    const int t  = threadIdx.x;
    const int c4 = t & 255;              // float4 column
    const int g  = t >> 8;               // row-group 0/1
    __shared__ float4 lds[512];

    const float4* base = reinterpret_cast<const float4*>(vals)
                       + (size_t)(n * SEQ + c * 16 + g * 8) * (EMBED / 4);
    float4 acc = make_float4(0.f, 0.f, 0.f, 0.f);
    #pragma unroll
    for (int r = 0; r < 8; ++r) {
        float4 v = base[(size_t)r * (EMBED / 4) + c4];
        acc.x += v.x; acc.y += v.y; acc.z += v.z; acc.w += v.w;
    }
    lds[t] = acc;
    __syncthreads();
    if (t < 256) {
        float4 a = lds[t], bq = lds[t + 256];
        a.x += bq.x; a.y += bq.y; a.z += bq.z; a.w += bq.w;
        reinterpret_cast<float4*>(part)[(size_t)b * (EMBED / 4) + t] = a;
    }
}

// ---------------------------------------------------------------------------
// K2: fused matvec + broadcast, now on ALL 256 CUs.
// grid = 256 blocks x 256 threads. Block b: batch n = b>>7, r = b&127,
// col-stripe s16 = r>>1 (16 output cols), row-half hh = r&1 (1024 s-rows).
//   1) Sv = reduce of CH partials (L2/L3-resident)
//   2) Vflat[h*64+d] = sum_e Wv[d][e] * Sv[h*64+e]
//   3) 16 Wo-row dots (wave w -> 4 outputs, float4 + 64-lane shuffle reduce)
//   4) write these 16 cols for 1024 s-rows (64 B contiguous per row = full
//      sectors; wave covers 16 rows/iter).
// ---------------------------------------------------------------------------
__global__ __launch_bounds__(256) void mv_bcast(const float* __restrict__ part,
                                                const float* __restrict__ Wv,
                                                const float* __restrict__ Wo,
                                                const float* __restrict__ bo,
                                                float4* __restrict__ out4) {
    const int b   = blockIdx.x;
    const int n   = b >> 7;
    const int r   = b & 127;
    const int s16 = r >> 1;
    const int hh  = r & 1;
    const int t   = threadIdx.x;
    __shared__ float svl[EMBED];
    __shared__ float vfl[EMBED];
    __shared__ __align__(16) float rsl[16];

    // 1) reduce CH partials for batch n (thread t owns float4-col t)
    {
        const float4* p = reinterpret_cast<const float4*>(part)
                        + (size_t)n * CH * (EMBED / 4) + t;
        float4 acc = make_float4(0.f, 0.f, 0.f, 0.f);
        #pragma unroll 8
        for (int c = 0; c < CH; ++c) {
            float4 v = p[(size_t)c * (EMBED / 4)];
            acc.x += v.x; acc.y += v.y; acc.z += v.z; acc.w += v.w;
        }
        reinterpret_cast<float4*>(svl)[t] = acc;
    }
    __syncthreads();

    // 2) Vflat: per-head 64x64 matvec (each thread 4 outputs)
    for (int o = t; o < EMBED; o += 256) {
        const int h = o >> 6, d = o & 63;
        const float* wr = Wv + d * HDIM;
        const float* sr = svl + h * HDIM;
        float a = 0.f;
        #pragma unroll
        for (int e = 0; e < HDIM; ++e) a += wr[e] * sr[e];
        vfl[o] = a;
    }
    __syncthreads();

    // 3) this block's 16 outputs (wave w -> 4 outputs)
    const int wave = t >> 6;
    const int lane = t & 63;
    float4 vv[4];
    #pragma unroll
    for (int it = 0; it < 4; ++it)
        vv[it] = reinterpret_cast<const float4*>(vfl)[it * 64 + lane];

    const float4* Wo4 = reinterpret_cast<const float4*>(Wo);
    #pragma unroll
    for (int j = 0; j < 4; ++j) {
        const int o = s16 * 16 + wave * 4 + j;
        float acc = 0.f;
        #pragma unroll
        for (int it = 0; it < 4; ++it) {
            float4 w4 = Wo4[(size_t)o * (EMBED / 4) + it * 64 + lane];
            acc += w4.x * vv[it].x + w4.y * vv[it].y
                 + w4.z * vv[it].z + w4.w * vv[it].w;
        }
        #pragma unroll
        for (int off = 32; off >= 1; off >>= 1)
            acc += __shfl_xor(acc, off);
        if (lane == 0) rsl[wave * 4 + j] = acc + bo[o];
    }
    __syncthreads();

    // 4) broadcast: 16 cols x 1024 rows for row-half hh
    const float4 val = reinterpret_cast<const float4*>(rsl)[t & 3];
    float4* op = out4 + (size_t)(n * SEQ + hh * 1024 + (t >> 2)) * (EMBED / 4)
               + s16 * 4 + (t & 3);
    #pragma unroll
    for (int k = 0; k < 16; ++k)
        op[(size_t)k * 64 * (EMBED / 4)] = val;
}

// ---------------------------------------------------------------------------
extern "C" void kernel_launch(void* const* d_in, const int* in_sizes, int n_in,
                              void* d_out, int out_size, void* d_ws, size_t ws_size,
                              hipStream_t stream) {
    // setup_inputs order: values, keys, queries, mask, Wv, Wk, Wq, Wo, bo
    const float* vals = (const float*)d_in[0];
    const float* Wv   = (const float*)d_in[4];
    const float* Wo   = (const float*)d_in[7];
    const float* bo   = (const float*)d_in[8];

    float* part = (float*)d_ws;          // NB*CH*EMBED floats (1 MB)

    colsum_part<<<NB * CH, 512, 0, stream>>>(vals, part);
    mv_bcast<<<256, 256, 0, stream>>>(part, Wv, Wo, bo, (float4*)d_out);
}